// Round 10
// baseline (684.912 us; speedup 1.0000x reference)
//
#include <hip/hip_runtime.h>

typedef __attribute__((ext_vector_type(8)))  short short8;   // 8 x bf16 fragment
typedef __attribute__((ext_vector_type(4)))  float f32x4;
typedef __attribute__((ext_vector_type(16))) float f32x16;

constexpr int N_ROWS = 131072;
constexpr int K_CB   = 4096;
constexpr int D_DIM  = 64;
// planes pre-scaled: x*2^8, c*2^7 -> acc = m*2^15 directly (key units)
constexpr float XSCALE = 256.0f;
constexpr float CSCALE = 128.0f;
constexpr float BSCALE = 32768.0f;
// flag threshold in key-value units (2^-15 m-units): 1.25e-3*32768=41, +trunc slack -> 48
constexpr int EPS_KEY = 48;

// ---- ws layout (bytes) ----
constexpr size_t CTR_OFF   = 0;                         // int counter
constexpr size_t CSQ_OFF   = 64;                        // 4096 f32 (|c|^2, for repair)
constexpr size_t CB4_OFF   = CSQ_OFF + 16384;           // 4096 x 4 f32 (-0.5|c|^2*2^15 replicated)
constexpr size_t CBH_OFF   = CB4_OFF + 65536;           // 4096*64 bf16 hi, pre-swizzled, *2^7
constexpr size_t CBL_OFF   = CBH_OFF + 524288;          // lo plane, pre-swizzled, *2^7
constexpr size_t LIST_OFF  = CBL_OFF + 524288;          // flagged-row list

#define MFMA32(a, b, c) __builtin_amdgcn_mfma_f32_32x32x16_bf16((a), (b), (c), 0, 0, 0)

constexpr int BUF_BYTES = 17408;   // hi 8K | lo 8K | cbias 1K

__device__ __forceinline__ unsigned short f2bf(float f) {
    unsigned int u = __builtin_bit_cast(unsigned int, f);
    u = (u + 0x7fffu + ((u >> 16) & 1u)) >> 16;   // RTNE
    return (unsigned short)u;
}
__device__ __forceinline__ float bf2f(unsigned short h) {
    return __builtin_bit_cast(float, ((unsigned int)h) << 16);
}
__device__ __forceinline__ int med3_i32(int a, int b, int c) {
    int r;
    asm("v_med3_i32 %0, %1, %2, %3" : "=v"(r) : "v"(a), "v"(b), "v"(c));
    return r;
}
__device__ __forceinline__ int imax(int a, int b) { return a > b ? a : b; }

// swizzled 16B fragment read from a [rows][128B] tile; chunk (2*ks+g) XOR (row&7)
__device__ __forceinline__ short8 ldfrag32(const unsigned char* base, int row, int g, int ks) {
    const int slot = ((2 * ks + g) ^ (row & 7));
    uint4 v = *(const uint4*)(base + row * 128 + slot * 16);
    return __builtin_bit_cast(short8, v);
}

// ---- prep: |c|^2 + replicated -0.5|c|^2*2^15 + counter init ----
__global__ __launch_bounds__(256)
void prep_csq(const float* __restrict__ cb, float* __restrict__ csq,
              float4* __restrict__ cbias4, int* __restrict__ counter) {
    const int k = blockIdx.x * 256 + threadIdx.x;
    if (k == 0) *counter = 0;
    const float4* row = (const float4*)(cb + (size_t)k * D_DIM);
    float s = 0.f;
    #pragma unroll
    for (int i = 0; i < 16; ++i) {
        float4 v = row[i];
        s = fmaf(v.x, v.x, s); s = fmaf(v.y, v.y, s);
        s = fmaf(v.z, v.z, s); s = fmaf(v.w, v.w, s);
    }
    csq[k] = s;
    const float n = -0.5f * s * BSCALE;
    cbias4[k] = make_float4(n, n, n, n);
}

// ---- prep: split cb*2^7 into hi/lo bf16 planes, PRE-SWIZZLED (slot ^= row&7) ----
__global__ __launch_bounds__(256)
void prep_split(const float* __restrict__ cb, unsigned char* __restrict__ cbh,
                unsigned char* __restrict__ cbl) {
    const int id  = blockIdx.x * 256 + threadIdx.x;   // 32768 = 4096 rows * 8 chunks
    const int row = id >> 3, s = id & 7;
    const float4* src = (const float4*)(cb + (size_t)row * D_DIM + s * 8);
    float4 v0 = src[0], v1 = src[1];
    float f[8] = {v0.x * CSCALE, v0.y * CSCALE, v0.z * CSCALE, v0.w * CSCALE,
                  v1.x * CSCALE, v1.y * CSCALE, v1.z * CSCALE, v1.w * CSCALE};
    unsigned int hw[4], lw[4];
    #pragma unroll
    for (int i = 0; i < 4; ++i) {
        unsigned short h0 = f2bf(f[2*i]),     l0 = f2bf(f[2*i]     - bf2f(h0));
        unsigned short h1 = f2bf(f[2*i + 1]), l1 = f2bf(f[2*i + 1] - bf2f(h1));
        hw[i] = (unsigned int)h0 | ((unsigned int)h1 << 16);
        lw[i] = (unsigned int)l0 | ((unsigned int)l1 << 16);
    }
    const int slot = s ^ (row & 7);
    *(uint4*)(cbh + (size_t)row * 128 + slot * 16) = make_uint4(hw[0], hw[1], hw[2], hw[3]);
    *(uint4*)(cbl + (size_t)row * 128 + slot * 16) = make_uint4(lw[0], lw[1], lw[2], lw[3]);
}

// ---- stage one 64-code tile: hi 8K | lo 8K | cbias 1K — 5 loads per wave, uniform ----
__device__ __forceinline__ void stage_tile(const unsigned char* __restrict__ cbh,
                                           const unsigned char* __restrict__ cbl,
                                           const float4* __restrict__ cbias4,
                                           unsigned char* sm, int T, int wid, int lane) {
    const unsigned char* sh = cbh + (size_t)T * 8192;
    const unsigned char* sl = cbl + (size_t)T * 8192;
    #pragma unroll
    for (int p = 0; p < 2; ++p) {
        const int chunk = wid * 2 + p;
        __builtin_amdgcn_global_load_lds(
            (const __attribute__((address_space(1))) void*)(sh + chunk * 1024 + lane * 16),
            (__attribute__((address_space(3))) void*)(sm + chunk * 1024), 16, 0, 0);
        __builtin_amdgcn_global_load_lds(
            (const __attribute__((address_space(1))) void*)(sl + chunk * 1024 + lane * 16),
            (__attribute__((address_space(3))) void*)(sm + 8192 + chunk * 1024), 16, 0, 0);
    }
    __builtin_amdgcn_global_load_lds(
        (const __attribute__((address_space(1))) void*)
            ((const unsigned char*)cbias4 + (size_t)T * 1024 + wid * 256 + lane * 4),
        (__attribute__((address_space(3))) void*)(sm + 16384 + wid * 256), 4, 0, 0);
}

// ---- main: counted-vmcnt pipeline + prescaled int-key top-2, 4 blocks/CU ----
__global__ __launch_bounds__(256, 4)
void vq_main_mfma(const float* __restrict__ z,
                  const float* __restrict__ cb,
                  const unsigned char* __restrict__ cbh,
                  const unsigned char* __restrict__ cbl,
                  const float4* __restrict__ cbias4,
                  int* __restrict__ list,
                  int* __restrict__ counter, float* __restrict__ out) {
    __shared__ __align__(16) unsigned char sm[2][BUF_BYTES];   // 34816 B
    unsigned char* smf = &sm[0][0];
    const int t = threadIdx.x, lane = t & 63, wid = t >> 6;
    const int g = lane >> 5, colv = lane & 31;
    const int n0 = blockIdx.x * 128;
    const int wbase = wid * 32;

    // ---- stage A tile (128 rows of z*2^8) hi/lo swizzled into LDS (spans both buffers) ----
    #pragma unroll
    for (int p = 0; p < 4; ++p) {
        const int id = t + p * 256;          // 1024 = 128 rows * 8 chunks
        const int row = id >> 3, s = id & 7;
        const float4* src = (const float4*)(z + (size_t)(n0 + row) * D_DIM + s * 8);
        float4 v0 = src[0], v1 = src[1];
        float f[8] = {v0.x * XSCALE, v0.y * XSCALE, v0.z * XSCALE, v0.w * XSCALE,
                      v1.x * XSCALE, v1.y * XSCALE, v1.z * XSCALE, v1.w * XSCALE};
        unsigned int hw[4], lw[4];
        #pragma unroll
        for (int i = 0; i < 4; ++i) {
            unsigned short h0 = f2bf(f[2*i]),     l0 = f2bf(f[2*i]     - bf2f(h0));
            unsigned short h1 = f2bf(f[2*i + 1]), l1 = f2bf(f[2*i + 1] - bf2f(h1));
            hw[i] = (unsigned int)h0 | ((unsigned int)h1 << 16);
            lw[i] = (unsigned int)l0 | ((unsigned int)l1 << 16);
        }
        const int slot = s ^ (row & 7);
        *(uint4*)(&smf[row * 128 + slot * 16])         = make_uint4(hw[0], hw[1], hw[2], hw[3]);
        *(uint4*)(&smf[16384 + row * 128 + slot * 16]) = make_uint4(lw[0], lw[1], lw[2], lw[3]);
    }
    __syncthreads();

    short8 ah[4], al[4];
    {
        const int arow = wbase + colv;
        #pragma unroll
        for (int ks = 0; ks < 4; ++ks) {
            ah[ks] = ldfrag32(smf,         arow, g, ks);
            al[ks] = ldfrag32(smf + 16384, arow, g, ks);
        }
    }
    __syncthreads();   // all waves done reading A; buffers free for B staging

    // per-lane fragment-read offsets (kernel-invariant): reg + immediate ds_reads
    int v_off[4];
    #pragma unroll
    for (int ks = 0; ks < 4; ++ks)
        v_off[ks] = (((2 * ks + g) ^ (colv & 7)) * 16) + colv * 128;
    const int cb_off = colv * 16;

    // packed-key top-2 state: 32 VGPRs total, no index array
    int k1[16], k2[16];
    #pragma unroll
    for (int j = 0; j < 16; ++j) { k1[j] = INT_MIN; k2[j] = INT_MIN; }

#define COMPUTE_TILE(BUF, TID)                                                      \
    do {                                                                            \
        const unsigned char* bp = smf + (BUF) * BUF_BYTES;                          \
        const int inv0 = 127 - (TID) * 2;                                           \
        int keyA[16];                                                               \
        _Pragma("unroll")                                                           \
        for (int ct = 0; ct < 2; ++ct) {                                            \
            short8 bh[4], bl[4];                                                    \
            _Pragma("unroll")                                                       \
            for (int ks = 0; ks < 4; ++ks) {                                        \
                bh[ks] = __builtin_bit_cast(short8,                                 \
                    *(const uint4*)(bp + v_off[ks] + ct * 4096));                   \
                bl[ks] = __builtin_bit_cast(short8,                                 \
                    *(const uint4*)(bp + 8192 + v_off[ks] + ct * 4096));            \
            }                                                                       \
            const f32x4 cbv = *(const f32x4*)(bp + 16384 + ct * 512 + cb_off);      \
            f32x16 acc;                                                             \
            _Pragma("unroll")                                                       \
            for (int q = 0; q < 16; ++q) acc[q] = cbv[q & 3];                       \
            __builtin_amdgcn_s_setprio(1);                                          \
            _Pragma("unroll")                                                       \
            for (int ks = 0; ks < 4; ++ks) acc = MFMA32(ah[ks], bh[ks], acc);       \
            _Pragma("unroll")                                                       \
            for (int ks = 0; ks < 4; ++ks) acc = MFMA32(al[ks], bh[ks], acc);       \
            _Pragma("unroll")                                                       \
            for (int ks = 0; ks < 4; ++ks) acc = MFMA32(ah[ks], bl[ks], acc);       \
            __builtin_amdgcn_s_setprio(0);                                          \
            if (ct == 0) {                                                          \
                _Pragma("unroll")                                                   \
                for (int j = 0; j < 16; ++j) {                                      \
                    const int ia = (int)acc[j];          /* cvt: acc is m*2^15 */   \
                    keyA[j] = (int)((unsigned)ia << 7) | inv0;                      \
                }                                                                   \
            } else {                                                                \
                _Pragma("unroll")                                                   \
                for (int j = 0; j < 16; ++j) {                                      \
                    const int ib = (int)acc[j];                                     \
                    const int kB = (int)((unsigned)ib << 7) | (inv0 - 1);           \
                    const int med = med3_i32(k1[j], keyA[j], kB);                   \
                    k1[j] = imax(k1[j], imax(keyA[j], kB));                         \
                    k2[j] = imax(k2[j], med);                                       \
                }                                                                   \
            }                                                                       \
        }                                                                           \
    } while (0)

    // prologue: stage tile 0 into buf0
    stage_tile(cbh, cbl, cbias4, smf, 0, wid, lane);

    for (int T = 0; T < 64; T += 2) {
        // even phase: compute tile T from buf0
        __builtin_amdgcn_s_barrier();                      // all done reading buf1 (tile T-1)
        stage_tile(cbh, cbl, cbias4, smf + BUF_BYTES, T + 1, wid, lane);
        asm volatile("s_waitcnt vmcnt(5)" ::: "memory");   // my tile-T loads landed
        __builtin_amdgcn_s_barrier();                      // everyone's landed
        COMPUTE_TILE(0, T);
        // odd phase: compute tile T+1 from buf1
        __builtin_amdgcn_s_barrier();                      // all done reading buf0 (tile T)
        if (T + 2 < 64) {
            stage_tile(cbh, cbl, cbias4, smf, T + 2, wid, lane);
            asm volatile("s_waitcnt vmcnt(5)" ::: "memory");
        } else {
            asm volatile("s_waitcnt vmcnt(0)" ::: "memory");
        }
        __builtin_amdgcn_s_barrier();
        COMPUTE_TILE(1, T + 1);
    }
#undef COMPUTE_TILE

    __syncthreads();   // drain everything before LDS reuse

    // cross-lane argmax over 32 code-columns on packed keys
    int* bidx_lds = (int*)&sm[0][0];
    #pragma unroll
    for (int j = 0; j < 16; ++j) {
        int v1 = k1[j], v2 = k2[j]; int cj = colv;
        #pragma unroll
        for (int msk = 1; msk < 32; msk <<= 1) {
            const int ov1 = __shfl_xor(v1, msk);
            const int ov2 = __shfl_xor(v2, msk);
            const int oc  = __shfl_xor(cj, msk);
            const bool take = (ov1 > v1) || (ov1 == v1 && oc < cj);
            const int nv2 = imax(take ? v1 : v2, take ? ov2 : ov1);
            v1 = take ? ov1 : v1; cj = take ? oc : cj; v2 = nv2;
        }
        if ((lane & 31) == 0) {
            const int tc  = 127 - (v1 & 127);              // tile*2 + ct
            const int idx = tc * 32 + cj;
            const int rloc = wbase + (j & 3) + 8 * (j >> 2) + 4 * g;
            bidx_lds[rloc] = idx;
            if ((v1 >> 7) - (v2 >> 7) < EPS_KEY) {
                const int p = atomicAdd(counter, 1);
                list[p] = n0 + rloc;
            }
        }
    }
    __syncthreads();

    // fused gather: write both output slices for this block's 128 rows
    const float4* cb4 = (const float4*)cb;
    float4* out4 = (float4*)out;
    #pragma unroll
    for (int p = 0; p < 8; ++p) {
        const int id  = t + p * 256;       // 2048 = 128 rows * 16 chunks
        const int row = id >> 4, c4 = id & 15;
        const int k = bidx_lds[row];
        const float4 v = cb4[(size_t)k * 16 + c4];
        out4[(size_t)(n0 + row) * 16 + c4] = v;
        out4[(size_t)N_ROWS * 16 + (size_t)(n0 + row) * 16 + c4] = v;
    }
}

// ---- repair: exact fp32 argmin for flagged rows (x register-resident, coalesced) ----
__global__ __launch_bounds__(256)
void repair_kernel(const float* __restrict__ z, const float* __restrict__ cb,
                   const float* __restrict__ csq, const int* __restrict__ list,
                   const int* __restrict__ counter, float* __restrict__ out) {
    __shared__ float4 xs4[16];
    __shared__ float rv[4];
    __shared__ int   ri[4];
    __shared__ int   fi_s;
    const int cnt = counter[0];
    const int t = threadIdx.x;
    for (int e = blockIdx.x; e < cnt; e += gridDim.x) {
        const int row = list[e];
        __syncthreads();
        if (t < 16) xs4[t] = ((const float4*)(z + (size_t)row * D_DIM))[t];
        __syncthreads();
        float4 xr[16];
        #pragma unroll
        for (int i = 0; i < 16; ++i) xr[i] = xs4[i];   // LDS broadcast -> registers
        float bv = __builtin_inff(); int bi = 0;
        #pragma unroll 2
        for (int i = 0; i < 16; ++i) {
            const int k = i * 256 + t;                 // coalesced across threads
            const float4* cr = (const float4*)(cb + (size_t)k * D_DIM);
            float dot = 0.f;
            #pragma unroll
            for (int q = 0; q < 16; ++q) {
                const float4 v = cr[q];
                dot = fmaf(v.x, xr[q].x, dot);
                dot = fmaf(v.y, xr[q].y, dot);
                dot = fmaf(v.z, xr[q].z, dot);
                dot = fmaf(v.w, xr[q].w, dot);
            }
            const float d = fmaf(dot, -2.f, csq[k]);
            if (d < bv) { bv = d; bi = k; }
        }
        #pragma unroll
        for (int msk = 1; msk < 64; msk <<= 1) {
            const float ov = __shfl_xor(bv, msk);
            const int   oi = __shfl_xor(bi, msk);
            if (ov < bv || (ov == bv && oi < bi)) { bv = ov; bi = oi; }
        }
        if ((t & 63) == 0) { rv[t >> 6] = bv; ri[t >> 6] = bi; }
        __syncthreads();
        if (t == 0) {
            float fb = rv[0]; int fi = ri[0];
            #pragma unroll
            for (int w = 1; w < 4; ++w)
                if (rv[w] < fb || (rv[w] == fb && ri[w] < fi)) { fb = rv[w]; fi = ri[w]; }
            fi_s = fi;
        }
        __syncthreads();
        if (t < 32) {
            const int dest = t >> 4, c4 = t & 15;
            const float4 v = ((const float4*)cb)[(size_t)fi_s * 16 + c4];
            float4* dst = (float4*)out + (size_t)dest * N_ROWS * 16 + (size_t)row * 16 + c4;
            *dst = v;
        }
        __syncthreads();
    }
}

extern "C" void kernel_launch(void* const* d_in, const int* in_sizes, int n_in,
                              void* d_out, int out_size, void* d_ws, size_t ws_size,
                              hipStream_t stream) {
    const float* z  = (const float*)d_in[0];
    const float* cb = (const float*)d_in[1];
    float* out = (float*)d_out;
    unsigned char* ws = (unsigned char*)d_ws;

    int*    counter = (int*)(ws + CTR_OFF);
    float*  csq     = (float*)(ws + CSQ_OFF);
    float4* cbias4  = (float4*)(ws + CB4_OFF);
    unsigned char* cbh = ws + CBH_OFF;
    unsigned char* cbl = ws + CBL_OFF;
    int* list  = (int*)(ws + LIST_OFF);

    prep_csq<<<K_CB / 256, 256, 0, stream>>>(cb, csq, cbias4, counter);
    prep_split<<<(K_CB * 8) / 256, 256, 0, stream>>>(cb, cbh, cbl);
    vq_main_mfma<<<N_ROWS / 128, 256, 0, stream>>>(z, cb, cbh, cbl, cbias4,
                                                   list, counter, out);
    repair_kernel<<<2048, 256, 0, stream>>>(z, cb, csq, list, counter, out);
}

// Round 11
// 271.872 us; speedup vs baseline: 2.5192x; 2.5192x over previous
//
#include <hip/hip_runtime.h>

typedef __attribute__((ext_vector_type(8)))  short short8;   // 8 x bf16 fragment
typedef __attribute__((ext_vector_type(4)))  float f32x4;
typedef __attribute__((ext_vector_type(16))) float f32x16;

constexpr int N_ROWS = 131072;
constexpr int K_CB   = 4096;
constexpr int D_DIM  = 64;
// planes pre-scaled: x*2^8, c*2^7 -> acc = m*2^15 directly (key units)
constexpr float XSCALE = 256.0f;
constexpr float CSCALE = 128.0f;
constexpr float BSCALE = 32768.0f;
// flag threshold in key-value units (2^-15 m-units): 1.25e-3*32768=41, +trunc slack -> 48
constexpr int EPS_KEY = 48;

// ---- ws layout (bytes) ----
constexpr size_t CTR_OFF   = 0;                         // int counter
constexpr size_t CSQ_OFF   = 64;                        // 4096 f32 (|c|^2, for repair)
constexpr size_t CB4_OFF   = CSQ_OFF + 16384;           // 4096 x 4 f32 (-0.5|c|^2*2^15 replicated)
constexpr size_t CBH_OFF   = CB4_OFF + 65536;           // hi plane, chunk-major tiles, *2^7
constexpr size_t CBL_OFF   = CBH_OFF + 524288;          // lo plane, chunk-major tiles, *2^7
constexpr size_t LIST_OFF  = CBL_OFF + 524288;          // flagged-row list

#define MFMA32(a, b, c) __builtin_amdgcn_mfma_f32_32x32x16_bf16((a), (b), (c), 0, 0, 0)

constexpr int BUF_BYTES = 17408;   // hi 8K | lo 8K | cbias 1K

__device__ __forceinline__ unsigned short f2bf(float f) {
    unsigned int u = __builtin_bit_cast(unsigned int, f);
    u = (u + 0x7fffu + ((u >> 16) & 1u)) >> 16;   // RTNE
    return (unsigned short)u;
}
__device__ __forceinline__ float bf2f(unsigned short h) {
    return __builtin_bit_cast(float, ((unsigned int)h) << 16);
}
__device__ __forceinline__ int med3_i32(int a, int b, int c) {
    int r;
    asm("v_med3_i32 %0, %1, %2, %3" : "=v"(r) : "v"(a), "v"(b), "v"(c));
    return r;
}
__device__ __forceinline__ int max3_i32(int a, int b, int c) {
    int r;
    asm("v_max3_i32 %0, %1, %2, %3" : "=v"(r) : "v"(a), "v"(b), "v"(c));
    return r;
}
__device__ __forceinline__ int imax(int a, int b) { return a > b ? a : b; }

// swizzled 16B fragment read from the A LDS tile; chunk (2*ks+g) XOR (row&7)
__device__ __forceinline__ short8 ldfrag32(const unsigned char* base, int row, int g, int ks) {
    const int slot = ((2 * ks + g) ^ (row & 7));
    uint4 v = *(const uint4*)(base + row * 128 + slot * 16);
    return __builtin_bit_cast(short8, v);
}

// ---- prep: |c|^2 + replicated -0.5|c|^2*2^15 + counter init ----
__global__ __launch_bounds__(256)
void prep_csq(const float* __restrict__ cb, float* __restrict__ csq,
              float4* __restrict__ cbias4, int* __restrict__ counter) {
    const int k = blockIdx.x * 256 + threadIdx.x;
    if (k == 0) *counter = 0;
    const float4* row = (const float4*)(cb + (size_t)k * D_DIM);
    float s = 0.f;
    #pragma unroll
    for (int i = 0; i < 16; ++i) {
        float4 v = row[i];
        s = fmaf(v.x, v.x, s); s = fmaf(v.y, v.y, s);
        s = fmaf(v.z, v.z, s); s = fmaf(v.w, v.w, s);
    }
    csq[k] = s;
    const float n = -0.5f * s * BSCALE;
    cbias4[k] = make_float4(n, n, n, n);
}

// ---- prep: split cb*2^7 into hi/lo planes, CHUNK-MAJOR per 64-row tile ----
// dest byte (per plane) = tile*8192 + chunk*1024 + localrow*16
// -> in-kernel B reads become lane-consecutive 16B (conflict-free b128)
__global__ __launch_bounds__(256)
void prep_split(const float* __restrict__ cb, unsigned char* __restrict__ cbh,
                unsigned char* __restrict__ cbl) {
    const int id  = blockIdx.x * 256 + threadIdx.x;   // 32768 = 4096 rows * 8 chunks
    const int row = id >> 3, s = id & 7;              // s = k-chunk (8 floats)
    const float4* src = (const float4*)(cb + (size_t)row * D_DIM + s * 8);
    float4 v0 = src[0], v1 = src[1];
    float f[8] = {v0.x * CSCALE, v0.y * CSCALE, v0.z * CSCALE, v0.w * CSCALE,
                  v1.x * CSCALE, v1.y * CSCALE, v1.z * CSCALE, v1.w * CSCALE};
    unsigned int hw[4], lw[4];
    #pragma unroll
    for (int i = 0; i < 4; ++i) {
        unsigned short h0 = f2bf(f[2*i]),     l0 = f2bf(f[2*i]     - bf2f(h0));
        unsigned short h1 = f2bf(f[2*i + 1]), l1 = f2bf(f[2*i + 1] - bf2f(h1));
        hw[i] = (unsigned int)h0 | ((unsigned int)h1 << 16);
        lw[i] = (unsigned int)l0 | ((unsigned int)l1 << 16);
    }
    const size_t dst = (size_t)(row >> 6) * 8192 + (size_t)s * 1024 + (size_t)(row & 63) * 16;
    *(uint4*)(cbh + dst) = make_uint4(hw[0], hw[1], hw[2], hw[3]);
    *(uint4*)(cbl + dst) = make_uint4(lw[0], lw[1], lw[2], lw[3]);
}

// ---- stage one 64-code tile: hi 8K | lo 8K | cbias 1K — 5 loads per wave, uniform ----
__device__ __forceinline__ void stage_tile(const unsigned char* __restrict__ cbh,
                                           const unsigned char* __restrict__ cbl,
                                           const float4* __restrict__ cbias4,
                                           unsigned char* sm, int T, int wid, int lane) {
    const unsigned char* sh = cbh + (size_t)T * 8192;
    const unsigned char* sl = cbl + (size_t)T * 8192;
    #pragma unroll
    for (int p = 0; p < 2; ++p) {
        const int chunk = wid * 2 + p;
        __builtin_amdgcn_global_load_lds(
            (const __attribute__((address_space(1))) void*)(sh + chunk * 1024 + lane * 16),
            (__attribute__((address_space(3))) void*)(sm + chunk * 1024), 16, 0, 0);
        __builtin_amdgcn_global_load_lds(
            (const __attribute__((address_space(1))) void*)(sl + chunk * 1024 + lane * 16),
            (__attribute__((address_space(3))) void*)(sm + 8192 + chunk * 1024), 16, 0, 0);
    }
    __builtin_amdgcn_global_load_lds(
        (const __attribute__((address_space(1))) void*)
            ((const unsigned char*)cbias4 + (size_t)T * 1024 + wid * 256 + lane * 4),
        (__attribute__((address_space(3))) void*)(sm + 16384 + wid * 256), 4, 0, 0);
}

// ---- main: counted-vmcnt pipeline, conflict-free B reads, int-key top-2 ----
__global__ __launch_bounds__(256, 3)
void vq_main_mfma(const float* __restrict__ z,
                  const float* __restrict__ cb,
                  const unsigned char* __restrict__ cbh,
                  const unsigned char* __restrict__ cbl,
                  const float4* __restrict__ cbias4,
                  int* __restrict__ list,
                  int* __restrict__ counter, float* __restrict__ out) {
    __shared__ __align__(16) unsigned char sm[2][BUF_BYTES];   // 34816 B
    unsigned char* smf = &sm[0][0];
    const int t = threadIdx.x, lane = t & 63, wid = t >> 6;
    const int g = lane >> 5, colv = lane & 31;
    const int n0 = blockIdx.x * 128;
    const int wbase = wid * 32;

    // ---- stage A tile (128 rows of z*2^8) hi/lo swizzled into LDS (spans both buffers) ----
    #pragma unroll
    for (int p = 0; p < 4; ++p) {
        const int id = t + p * 256;          // 1024 = 128 rows * 8 chunks
        const int row = id >> 3, s = id & 7;
        const float4* src = (const float4*)(z + (size_t)(n0 + row) * D_DIM + s * 8);
        float4 v0 = src[0], v1 = src[1];
        float f[8] = {v0.x * XSCALE, v0.y * XSCALE, v0.z * XSCALE, v0.w * XSCALE,
                      v1.x * XSCALE, v1.y * XSCALE, v1.z * XSCALE, v1.w * XSCALE};
        unsigned int hw[4], lw[4];
        #pragma unroll
        for (int i = 0; i < 4; ++i) {
            unsigned short h0 = f2bf(f[2*i]),     l0 = f2bf(f[2*i]     - bf2f(h0));
            unsigned short h1 = f2bf(f[2*i + 1]), l1 = f2bf(f[2*i + 1] - bf2f(h1));
            hw[i] = (unsigned int)h0 | ((unsigned int)h1 << 16);
            lw[i] = (unsigned int)l0 | ((unsigned int)l1 << 16);
        }
        const int slot = s ^ (row & 7);
        *(uint4*)(&smf[row * 128 + slot * 16])         = make_uint4(hw[0], hw[1], hw[2], hw[3]);
        *(uint4*)(&smf[16384 + row * 128 + slot * 16]) = make_uint4(lw[0], lw[1], lw[2], lw[3]);
    }
    __syncthreads();

    short8 ah[4], al[4];
    {
        const int arow = wbase + colv;
        #pragma unroll
        for (int ks = 0; ks < 4; ++ks) {
            ah[ks] = ldfrag32(smf,         arow, g, ks);
            al[ks] = ldfrag32(smf + 16384, arow, g, ks);
        }
    }
    __syncthreads();   // all waves done reading A; buffers free for B staging

    // B fragment base: chunk-major layout -> one base reg, rest immediates
    const int vb = g * 1024 + colv * 16;   // + ks*2048 + ct*512 (compile-time)
    const int cb_off = colv * 16;          // + ct*512

    // packed-key top-2 state: 32 VGPRs total, no index array
    int k1[16], k2[16];
    #pragma unroll
    for (int j = 0; j < 16; ++j) { k1[j] = INT_MIN; k2[j] = INT_MIN; }

#define COMPUTE_TILE(BUF, TID)                                                      \
    do {                                                                            \
        const unsigned char* bp = smf + (BUF) * BUF_BYTES;                          \
        const int inv0 = 127 - (TID) * 2;                                           \
        int keyA[16];                                                               \
        _Pragma("unroll")                                                           \
        for (int ct = 0; ct < 2; ++ct) {                                            \
            short8 bh[4], bl[4];                                                    \
            _Pragma("unroll")                                                       \
            for (int ks = 0; ks < 4; ++ks) {                                        \
                bh[ks] = __builtin_bit_cast(short8,                                 \
                    *(const uint4*)(bp + vb + ks * 2048 + ct * 512));               \
                bl[ks] = __builtin_bit_cast(short8,                                 \
                    *(const uint4*)(bp + 8192 + vb + ks * 2048 + ct * 512));        \
            }                                                                       \
            const f32x4 cbv = *(const f32x4*)(bp + 16384 + ct * 512 + cb_off);      \
            f32x16 acc;                                                             \
            _Pragma("unroll")                                                       \
            for (int q = 0; q < 16; ++q) acc[q] = cbv[q & 3];                       \
            __builtin_amdgcn_s_setprio(1);                                          \
            _Pragma("unroll")                                                       \
            for (int ks = 0; ks < 4; ++ks) acc = MFMA32(ah[ks], bh[ks], acc);       \
            _Pragma("unroll")                                                       \
            for (int ks = 0; ks < 4; ++ks) acc = MFMA32(al[ks], bh[ks], acc);       \
            _Pragma("unroll")                                                       \
            for (int ks = 0; ks < 4; ++ks) acc = MFMA32(ah[ks], bl[ks], acc);       \
            __builtin_amdgcn_s_setprio(0);                                          \
            if (ct == 0) {                                                          \
                _Pragma("unroll")                                                   \
                for (int j = 0; j < 16; ++j) {                                      \
                    const int ia = (int)acc[j];          /* cvt: acc is m*2^15 */   \
                    keyA[j] = (int)((unsigned)ia << 7) | inv0;                      \
                }                                                                   \
            } else {                                                                \
                _Pragma("unroll")                                                   \
                for (int j = 0; j < 16; ++j) {                                      \
                    const int ib = (int)acc[j];                                     \
                    const int kB = (int)((unsigned)ib << 7) | (inv0 - 1);           \
                    const int med = med3_i32(k1[j], keyA[j], kB);                   \
                    k1[j] = max3_i32(k1[j], keyA[j], kB);                           \
                    k2[j] = imax(k2[j], med);                                       \
                }                                                                   \
            }                                                                       \
        }                                                                           \
    } while (0)

    // prologue: stage tile 0 into buf0
    stage_tile(cbh, cbl, cbias4, smf, 0, wid, lane);

    for (int T = 0; T < 64; T += 2) {
        // even phase: compute tile T from buf0
        __builtin_amdgcn_s_barrier();                      // all done reading buf1 (tile T-1)
        stage_tile(cbh, cbl, cbias4, smf + BUF_BYTES, T + 1, wid, lane);
        asm volatile("s_waitcnt vmcnt(5)" ::: "memory");   // my tile-T loads landed
        __builtin_amdgcn_s_barrier();                      // everyone's landed
        COMPUTE_TILE(0, T);
        // odd phase: compute tile T+1 from buf1
        __builtin_amdgcn_s_barrier();                      // all done reading buf0 (tile T)
        if (T + 2 < 64) {
            stage_tile(cbh, cbl, cbias4, smf, T + 2, wid, lane);
            asm volatile("s_waitcnt vmcnt(5)" ::: "memory");
        } else {
            asm volatile("s_waitcnt vmcnt(0)" ::: "memory");
        }
        __builtin_amdgcn_s_barrier();
        COMPUTE_TILE(1, T + 1);
    }
#undef COMPUTE_TILE

    __syncthreads();   // drain everything before LDS reuse

    // cross-lane argmax over 32 code-columns on packed keys
    int* bidx_lds = (int*)&sm[0][0];
    #pragma unroll
    for (int j = 0; j < 16; ++j) {
        int v1 = k1[j], v2 = k2[j]; int cj = colv;
        #pragma unroll
        for (int msk = 1; msk < 32; msk <<= 1) {
            const int ov1 = __shfl_xor(v1, msk);
            const int ov2 = __shfl_xor(v2, msk);
            const int oc  = __shfl_xor(cj, msk);
            const bool take = (ov1 > v1) || (ov1 == v1 && oc < cj);
            const int nv2 = imax(take ? v1 : v2, take ? ov2 : ov1);
            v1 = take ? ov1 : v1; cj = take ? oc : cj; v2 = nv2;
        }
        if ((lane & 31) == 0) {
            const int tc  = 127 - (v1 & 127);              // tile*2 + ct
            const int idx = tc * 32 + cj;
            const int rloc = wbase + (j & 3) + 8 * (j >> 2) + 4 * g;
            bidx_lds[rloc] = idx;
            if ((v1 >> 7) - (v2 >> 7) < EPS_KEY) {
                const int p = atomicAdd(counter, 1);
                list[p] = n0 + rloc;
            }
        }
    }
    __syncthreads();

    // fused gather: write both output slices for this block's 128 rows
    const float4* cb4 = (const float4*)cb;
    float4* out4 = (float4*)out;
    #pragma unroll
    for (int p = 0; p < 8; ++p) {
        const int id  = t + p * 256;       // 2048 = 128 rows * 16 chunks
        const int row = id >> 4, c4 = id & 15;
        const int k = bidx_lds[row];
        const float4 v = cb4[(size_t)k * 16 + c4];
        out4[(size_t)(n0 + row) * 16 + c4] = v;
        out4[(size_t)N_ROWS * 16 + (size_t)(n0 + row) * 16 + c4] = v;
    }
}

// ---- repair: exact fp32 argmin for flagged rows (x register-resident, coalesced) ----
__global__ __launch_bounds__(256)
void repair_kernel(const float* __restrict__ z, const float* __restrict__ cb,
                   const float* __restrict__ csq, const int* __restrict__ list,
                   const int* __restrict__ counter, float* __restrict__ out) {
    __shared__ float4 xs4[16];
    __shared__ float rv[4];
    __shared__ int   ri[4];
    __shared__ int   fi_s;
    const int cnt = counter[0];
    const int t = threadIdx.x;
    for (int e = blockIdx.x; e < cnt; e += gridDim.x) {
        const int row = list[e];
        __syncthreads();
        if (t < 16) xs4[t] = ((const float4*)(z + (size_t)row * D_DIM))[t];
        __syncthreads();
        float4 xr[16];
        #pragma unroll
        for (int i = 0; i < 16; ++i) xr[i] = xs4[i];   // LDS broadcast -> registers
        float bv = __builtin_inff(); int bi = 0;
        #pragma unroll 2
        for (int i = 0; i < 16; ++i) {
            const int k = i * 256 + t;                 // coalesced across threads
            const float4* cr = (const float4*)(cb + (size_t)k * D_DIM);
            float dot = 0.f;
            #pragma unroll
            for (int q = 0; q < 16; ++q) {
                const float4 v = cr[q];
                dot = fmaf(v.x, xr[q].x, dot);
                dot = fmaf(v.y, xr[q].y, dot);
                dot = fmaf(v.z, xr[q].z, dot);
                dot = fmaf(v.w, xr[q].w, dot);
            }
            const float d = fmaf(dot, -2.f, csq[k]);
            if (d < bv) { bv = d; bi = k; }
        }
        #pragma unroll
        for (int msk = 1; msk < 64; msk <<= 1) {
            const float ov = __shfl_xor(bv, msk);
            const int   oi = __shfl_xor(bi, msk);
            if (ov < bv || (ov == bv && oi < bi)) { bv = ov; bi = oi; }
        }
        if ((t & 63) == 0) { rv[t >> 6] = bv; ri[t >> 6] = bi; }
        __syncthreads();
        if (t == 0) {
            float fb = rv[0]; int fi = ri[0];
            #pragma unroll
            for (int w = 1; w < 4; ++w)
                if (rv[w] < fb || (rv[w] == fb && ri[w] < fi)) { fb = rv[w]; fi = ri[w]; }
            fi_s = fi;
        }
        __syncthreads();
        if (t < 32) {
            const int dest = t >> 4, c4 = t & 15;
            const float4 v = ((const float4*)cb)[(size_t)fi_s * 16 + c4];
            float4* dst = (float4*)out + (size_t)dest * N_ROWS * 16 + (size_t)row * 16 + c4;
            *dst = v;
        }
        __syncthreads();
    }
}

extern "C" void kernel_launch(void* const* d_in, const int* in_sizes, int n_in,
                              void* d_out, int out_size, void* d_ws, size_t ws_size,
                              hipStream_t stream) {
    const float* z  = (const float*)d_in[0];
    const float* cb = (const float*)d_in[1];
    float* out = (float*)d_out;
    unsigned char* ws = (unsigned char*)d_ws;

    int*    counter = (int*)(ws + CTR_OFF);
    float*  csq     = (float*)(ws + CSQ_OFF);
    float4* cbias4  = (float4*)(ws + CB4_OFF);
    unsigned char* cbh = ws + CBH_OFF;
    unsigned char* cbl = ws + CBL_OFF;
    int* list  = (int*)(ws + LIST_OFF);

    prep_csq<<<K_CB / 256, 256, 0, stream>>>(cb, csq, cbias4, counter);
    prep_split<<<(K_CB * 8) / 256, 256, 0, stream>>>(cb, cbh, cbl);
    vq_main_mfma<<<N_ROWS / 128, 256, 0, stream>>>(z, cb, cbh, cbl, cbias4,
                                                   list, counter, out);
    repair_kernel<<<2048, 256, 0, stream>>>(z, cb, csq, list, counter, out);
}

// Round 12
// 265.985 us; speedup vs baseline: 2.5750x; 1.0221x over previous
//
#include <hip/hip_runtime.h>

typedef __attribute__((ext_vector_type(8)))  short short8;   // 8 x bf16 fragment
typedef __attribute__((ext_vector_type(4)))  float f32x4;
typedef __attribute__((ext_vector_type(16))) float f32x16;

constexpr int N_ROWS = 131072;
constexpr int K_CB   = 4096;
constexpr int D_DIM  = 64;
// planes pre-scaled: x*2^8, c*2^7 -> acc = m*2^15 directly (key units)
constexpr float XSCALE = 256.0f;
constexpr float CSCALE = 128.0f;
constexpr float BSCALE = 32768.0f;
// flag threshold in key-value units (2^-15 m-units): 1.25e-3*32768=41, +trunc slack -> 48
constexpr int EPS_KEY = 48;

// ---- ws layout (bytes) ----
constexpr size_t CTR_OFF   = 0;                         // int counter
constexpr size_t CSQ_OFF   = 64;                        // 4096 f32 (|c|^2, for repair)
constexpr size_t CB4_OFF   = CSQ_OFF + 16384;           // per-tile q-plane cbias: 64t x 4q x 64c x 16B
constexpr size_t CBH_OFF   = CB4_OFF + 262144;          // hi plane, chunk-major tiles, *2^7
constexpr size_t CBL_OFF   = CBH_OFF + 524288;          // lo plane, chunk-major tiles, *2^7
constexpr size_t LIST_OFF  = CBL_OFF + 524288;          // flagged-row list

#define MFMA32(a, b, c) __builtin_amdgcn_mfma_f32_32x32x16_bf16((a), (b), (c), 0, 0, 0)

constexpr int BUF_BYTES = 20480;   // hi 8K | lo 8K | cbias q-planes 4K

__device__ __forceinline__ unsigned short f2bf(float f) {
    unsigned int u = __builtin_bit_cast(unsigned int, f);
    u = (u + 0x7fffu + ((u >> 16) & 1u)) >> 16;   // RTNE
    return (unsigned short)u;
}
__device__ __forceinline__ float bf2f(unsigned short h) {
    return __builtin_bit_cast(float, ((unsigned int)h) << 16);
}
__device__ __forceinline__ int med3_i32(int a, int b, int c) {
    int r;
    asm("v_med3_i32 %0, %1, %2, %3" : "=v"(r) : "v"(a), "v"(b), "v"(c));
    return r;
}
__device__ __forceinline__ int max3_i32(int a, int b, int c) {
    int r;
    asm("v_max3_i32 %0, %1, %2, %3" : "=v"(r) : "v"(a), "v"(b), "v"(c));
    return r;
}
__device__ __forceinline__ int imax(int a, int b) { return a > b ? a : b; }

// swizzled 16B fragment read from the A LDS tile; chunk (2*ks+g) XOR (row&7)
__device__ __forceinline__ short8 ldfrag32(const unsigned char* base, int row, int g, int ks) {
    const int slot = ((2 * ks + g) ^ (row & 7));
    uint4 v = *(const uint4*)(base + row * 128 + slot * 16);
    return __builtin_bit_cast(short8, v);
}

// ---- prep: |c|^2 + q-plane replicated -0.5|c|^2*2^15 + counter init ----
__global__ __launch_bounds__(256)
void prep_csq(const float* __restrict__ cb, float* __restrict__ csq,
              unsigned char* __restrict__ cbias, int* __restrict__ counter) {
    const int k = blockIdx.x * 256 + threadIdx.x;
    if (k == 0) *counter = 0;
    const float4* row = (const float4*)(cb + (size_t)k * D_DIM);
    float s = 0.f;
    #pragma unroll
    for (int i = 0; i < 16; ++i) {
        float4 v = row[i];
        s = fmaf(v.x, v.x, s); s = fmaf(v.y, v.y, s);
        s = fmaf(v.z, v.z, s); s = fmaf(v.w, v.w, s);
    }
    csq[k] = s;
    const float n = -0.5f * s * BSCALE;
    const float4 nv = make_float4(n, n, n, n);
    const size_t base = (size_t)(k >> 6) * 4096 + (size_t)(k & 63) * 16;
    #pragma unroll
    for (int q = 0; q < 4; ++q)
        *(float4*)(cbias + base + q * 1024) = nv;
}

// ---- prep: split cb*2^7 into hi/lo planes, CHUNK-MAJOR per 64-row tile ----
__global__ __launch_bounds__(256)
void prep_split(const float* __restrict__ cb, unsigned char* __restrict__ cbh,
                unsigned char* __restrict__ cbl) {
    const int id  = blockIdx.x * 256 + threadIdx.x;   // 32768 = 4096 rows * 8 chunks
    const int row = id >> 3, s = id & 7;              // s = k-chunk (8 floats)
    const float4* src = (const float4*)(cb + (size_t)row * D_DIM + s * 8);
    float4 v0 = src[0], v1 = src[1];
    float f[8] = {v0.x * CSCALE, v0.y * CSCALE, v0.z * CSCALE, v0.w * CSCALE,
                  v1.x * CSCALE, v1.y * CSCALE, v1.z * CSCALE, v1.w * CSCALE};
    unsigned int hw[4], lw[4];
    #pragma unroll
    for (int i = 0; i < 4; ++i) {
        unsigned short h0 = f2bf(f[2*i]),     l0 = f2bf(f[2*i]     - bf2f(h0));
        unsigned short h1 = f2bf(f[2*i + 1]), l1 = f2bf(f[2*i + 1] - bf2f(h1));
        hw[i] = (unsigned int)h0 | ((unsigned int)h1 << 16);
        lw[i] = (unsigned int)l0 | ((unsigned int)l1 << 16);
    }
    const size_t dst = (size_t)(row >> 6) * 8192 + (size_t)s * 1024 + (size_t)(row & 63) * 16;
    *(uint4*)(cbh + dst) = make_uint4(hw[0], hw[1], hw[2], hw[3]);
    *(uint4*)(cbl + dst) = make_uint4(lw[0], lw[1], lw[2], lw[3]);
}

// ---- stage one 64-code tile: hi 8K | lo 8K | cbias 4K — 5 loads per wave, uniform ----
__device__ __forceinline__ void stage_tile(const unsigned char* __restrict__ cbh,
                                           const unsigned char* __restrict__ cbl,
                                           const unsigned char* __restrict__ cbias,
                                           unsigned char* sm, int T, int wid, int lane) {
    const unsigned char* sh = cbh + (size_t)T * 8192;
    const unsigned char* sl = cbl + (size_t)T * 8192;
    #pragma unroll
    for (int p = 0; p < 2; ++p) {
        const int chunk = wid * 2 + p;
        __builtin_amdgcn_global_load_lds(
            (const __attribute__((address_space(1))) void*)(sh + chunk * 1024 + lane * 16),
            (__attribute__((address_space(3))) void*)(sm + chunk * 1024), 16, 0, 0);
        __builtin_amdgcn_global_load_lds(
            (const __attribute__((address_space(1))) void*)(sl + chunk * 1024 + lane * 16),
            (__attribute__((address_space(3))) void*)(sm + 8192 + chunk * 1024), 16, 0, 0);
    }
    __builtin_amdgcn_global_load_lds(
        (const __attribute__((address_space(1))) void*)
            (cbias + (size_t)T * 4096 + wid * 1024 + lane * 16),
        (__attribute__((address_space(3))) void*)(sm + 16384 + wid * 1024), 16, 0, 0);
}

// ---- main: counted-vmcnt pipeline, LDS acc-init, no setprio fences ----
__global__ __launch_bounds__(256, 3)
void vq_main_mfma(const float* __restrict__ z,
                  const float* __restrict__ cb,
                  const unsigned char* __restrict__ cbh,
                  const unsigned char* __restrict__ cbl,
                  const unsigned char* __restrict__ cbias,
                  int* __restrict__ list,
                  int* __restrict__ counter, float* __restrict__ out) {
    __shared__ __align__(16) unsigned char sm[2][BUF_BYTES];   // 40960 B
    unsigned char* smf = &sm[0][0];
    const int t = threadIdx.x, lane = t & 63, wid = t >> 6;
    const int g = lane >> 5, colv = lane & 31;
    const int n0 = blockIdx.x * 128;
    const int wbase = wid * 32;

    // ---- stage A tile (128 rows of z*2^8) hi/lo swizzled into LDS (spans both buffers) ----
    #pragma unroll
    for (int p = 0; p < 4; ++p) {
        const int id = t + p * 256;          // 1024 = 128 rows * 8 chunks
        const int row = id >> 3, s = id & 7;
        const float4* src = (const float4*)(z + (size_t)(n0 + row) * D_DIM + s * 8);
        float4 v0 = src[0], v1 = src[1];
        float f[8] = {v0.x * XSCALE, v0.y * XSCALE, v0.z * XSCALE, v0.w * XSCALE,
                      v1.x * XSCALE, v1.y * XSCALE, v1.z * XSCALE, v1.w * XSCALE};
        unsigned int hw[4], lw[4];
        #pragma unroll
        for (int i = 0; i < 4; ++i) {
            unsigned short h0 = f2bf(f[2*i]),     l0 = f2bf(f[2*i]     - bf2f(h0));
            unsigned short h1 = f2bf(f[2*i + 1]), l1 = f2bf(f[2*i + 1] - bf2f(h1));
            hw[i] = (unsigned int)h0 | ((unsigned int)h1 << 16);
            lw[i] = (unsigned int)l0 | ((unsigned int)l1 << 16);
        }
        const int slot = s ^ (row & 7);
        *(uint4*)(&smf[row * 128 + slot * 16])         = make_uint4(hw[0], hw[1], hw[2], hw[3]);
        *(uint4*)(&smf[16384 + row * 128 + slot * 16]) = make_uint4(lw[0], lw[1], lw[2], lw[3]);
    }
    __syncthreads();

    short8 ah[4], al[4];
    {
        const int arow = wbase + colv;
        #pragma unroll
        for (int ks = 0; ks < 4; ++ks) {
            ah[ks] = ldfrag32(smf,         arow, g, ks);
            al[ks] = ldfrag32(smf + 16384, arow, g, ks);
        }
    }
    __syncthreads();   // all waves done reading A; buffers free for B staging

    // B fragment base: chunk-major layout -> one base reg, rest immediates
    const int vb = g * 1024 + colv * 16;   // + ks*2048 + ct*512 (compile-time)
    const int cb_off = colv * 16;          // + ct*512 + q*1024

    // packed-key top-2 state: 32 VGPRs total, no index array
    int k1[16], k2[16];
    #pragma unroll
    for (int j = 0; j < 16; ++j) { k1[j] = INT_MIN; k2[j] = INT_MIN; }

    union A16 { f32x16 v; f32x4 q[4]; };

#define COMPUTE_TILE(BUF, TID)                                                      \
    do {                                                                            \
        const unsigned char* bp = smf + (BUF) * BUF_BYTES;                          \
        const int inv0 = 127 - (TID) * 2;                                           \
        int keyA[16];                                                               \
        _Pragma("unroll")                                                           \
        for (int ct = 0; ct < 2; ++ct) {                                            \
            short8 bh[4], bl[4];                                                    \
            _Pragma("unroll")                                                       \
            for (int ks = 0; ks < 4; ++ks) {                                        \
                bh[ks] = __builtin_bit_cast(short8,                                 \
                    *(const uint4*)(bp + vb + ks * 2048 + ct * 512));               \
                bl[ks] = __builtin_bit_cast(short8,                                 \
                    *(const uint4*)(bp + 8192 + vb + ks * 2048 + ct * 512));        \
            }                                                                       \
            /* acc init = -0.5|c|^2*2^15 via 4 conflict-free ds_read_b128 */        \
            A16 au;                                                                 \
            _Pragma("unroll")                                                       \
            for (int q = 0; q < 4; ++q)                                             \
                au.q[q] = *(const f32x4*)(bp + 16384 + q * 1024 + ct * 512 + cb_off); \
            f32x16 acc = au.v;                                                      \
            _Pragma("unroll")                                                       \
            for (int ks = 0; ks < 4; ++ks) acc = MFMA32(ah[ks], bh[ks], acc);       \
            _Pragma("unroll")                                                       \
            for (int ks = 0; ks < 4; ++ks) acc = MFMA32(al[ks], bh[ks], acc);       \
            _Pragma("unroll")                                                       \
            for (int ks = 0; ks < 4; ++ks) acc = MFMA32(ah[ks], bl[ks], acc);       \
            if (ct == 0) {                                                          \
                _Pragma("unroll")                                                   \
                for (int j = 0; j < 16; ++j) {                                      \
                    const int ia = (int)acc[j];          /* cvt: acc is m*2^15 */   \
                    keyA[j] = (int)((unsigned)ia << 7) | inv0;                      \
                }                                                                   \
            } else {                                                                \
                _Pragma("unroll")                                                   \
                for (int j = 0; j < 16; ++j) {                                      \
                    const int ib = (int)acc[j];                                     \
                    const int kB = (int)((unsigned)ib << 7) | (inv0 - 1);           \
                    const int med = med3_i32(k1[j], keyA[j], kB);                   \
                    k1[j] = max3_i32(k1[j], keyA[j], kB);                           \
                    k2[j] = imax(k2[j], med);                                       \
                }                                                                   \
            }                                                                       \
        }                                                                           \
    } while (0)

    // prologue: stage tile 0 into buf0
    stage_tile(cbh, cbl, cbias, smf, 0, wid, lane);

    for (int T = 0; T < 64; T += 2) {
        // even phase: compute tile T from buf0
        __builtin_amdgcn_s_barrier();                      // all done reading buf1 (tile T-1)
        stage_tile(cbh, cbl, cbias, smf + BUF_BYTES, T + 1, wid, lane);
        asm volatile("s_waitcnt vmcnt(5)" ::: "memory");   // my tile-T loads landed
        __builtin_amdgcn_s_barrier();                      // everyone's landed
        COMPUTE_TILE(0, T);
        // odd phase: compute tile T+1 from buf1
        __builtin_amdgcn_s_barrier();                      // all done reading buf0 (tile T)
        if (T + 2 < 64) {
            stage_tile(cbh, cbl, cbias, smf, T + 2, wid, lane);
            asm volatile("s_waitcnt vmcnt(5)" ::: "memory");
        } else {
            asm volatile("s_waitcnt vmcnt(0)" ::: "memory");
        }
        __builtin_amdgcn_s_barrier();
        COMPUTE_TILE(1, T + 1);
    }
#undef COMPUTE_TILE

    __syncthreads();   // drain everything before LDS reuse

    // cross-lane argmax over 32 code-columns on packed keys
    int* bidx_lds = (int*)&sm[0][0];
    #pragma unroll
    for (int j = 0; j < 16; ++j) {
        int v1 = k1[j], v2 = k2[j]; int cj = colv;
        #pragma unroll
        for (int msk = 1; msk < 32; msk <<= 1) {
            const int ov1 = __shfl_xor(v1, msk);
            const int ov2 = __shfl_xor(v2, msk);
            const int oc  = __shfl_xor(cj, msk);
            const bool take = (ov1 > v1) || (ov1 == v1 && oc < cj);
            const int nv2 = imax(take ? v1 : v2, take ? ov2 : ov1);
            v1 = take ? ov1 : v1; cj = take ? oc : cj; v2 = nv2;
        }
        if ((lane & 31) == 0) {
            const int tc  = 127 - (v1 & 127);              // tile*2 + ct
            const int idx = tc * 32 + cj;
            const int rloc = wbase + (j & 3) + 8 * (j >> 2) + 4 * g;
            bidx_lds[rloc] = idx;
            if ((v1 >> 7) - (v2 >> 7) < EPS_KEY) {
                const int p = atomicAdd(counter, 1);
                list[p] = n0 + rloc;
            }
        }
    }
    __syncthreads();

    // fused gather: write both output slices for this block's 128 rows
    const float4* cb4 = (const float4*)cb;
    float4* out4 = (float4*)out;
    #pragma unroll
    for (int p = 0; p < 8; ++p) {
        const int id  = t + p * 256;       // 2048 = 128 rows * 16 chunks
        const int row = id >> 4, c4 = id & 15;
        const int k = bidx_lds[row];
        const float4 v = cb4[(size_t)k * 16 + c4];
        out4[(size_t)(n0 + row) * 16 + c4] = v;
        out4[(size_t)N_ROWS * 16 + (size_t)(n0 + row) * 16 + c4] = v;
    }
}

// ---- repair: exact fp32 argmin for flagged rows (x register-resident, coalesced) ----
__global__ __launch_bounds__(256)
void repair_kernel(const float* __restrict__ z, const float* __restrict__ cb,
                   const float* __restrict__ csq, const int* __restrict__ list,
                   const int* __restrict__ counter, float* __restrict__ out) {
    __shared__ float4 xs4[16];
    __shared__ float rv[4];
    __shared__ int   ri[4];
    __shared__ int   fi_s;
    const int cnt = counter[0];
    const int t = threadIdx.x;
    for (int e = blockIdx.x; e < cnt; e += gridDim.x) {
        const int row = list[e];
        __syncthreads();
        if (t < 16) xs4[t] = ((const float4*)(z + (size_t)row * D_DIM))[t];
        __syncthreads();
        float4 xr[16];
        #pragma unroll
        for (int i = 0; i < 16; ++i) xr[i] = xs4[i];   // LDS broadcast -> registers
        float bv = __builtin_inff(); int bi = 0;
        #pragma unroll 2
        for (int i = 0; i < 16; ++i) {
            const int k = i * 256 + t;                 // coalesced across threads
            const float4* cr = (const float4*)(cb + (size_t)k * D_DIM);
            float dot = 0.f;
            #pragma unroll
            for (int q = 0; q < 16; ++q) {
                const float4 v = cr[q];
                dot = fmaf(v.x, xr[q].x, dot);
                dot = fmaf(v.y, xr[q].y, dot);
                dot = fmaf(v.z, xr[q].z, dot);
                dot = fmaf(v.w, xr[q].w, dot);
            }
            const float d = fmaf(dot, -2.f, csq[k]);
            if (d < bv) { bv = d; bi = k; }
        }
        #pragma unroll
        for (int msk = 1; msk < 64; msk <<= 1) {
            const float ov = __shfl_xor(bv, msk);
            const int   oi = __shfl_xor(bi, msk);
            if (ov < bv || (ov == bv && oi < bi)) { bv = ov; bi = oi; }
        }
        if ((t & 63) == 0) { rv[t >> 6] = bv; ri[t >> 6] = bi; }
        __syncthreads();
        if (t == 0) {
            float fb = rv[0]; int fi = ri[0];
            #pragma unroll
            for (int w = 1; w < 4; ++w)
                if (rv[w] < fb || (rv[w] == fb && ri[w] < fi)) { fb = rv[w]; fi = ri[w]; }
            fi_s = fi;
        }
        __syncthreads();
        if (t < 32) {
            const int dest = t >> 4, c4 = t & 15;
            const float4 v = ((const float4*)cb)[(size_t)fi_s * 16 + c4];
            float4* dst = (float4*)out + (size_t)dest * N_ROWS * 16 + (size_t)row * 16 + c4;
            *dst = v;
        }
        __syncthreads();
    }
}

extern "C" void kernel_launch(void* const* d_in, const int* in_sizes, int n_in,
                              void* d_out, int out_size, void* d_ws, size_t ws_size,
                              hipStream_t stream) {
    const float* z  = (const float*)d_in[0];
    const float* cb = (const float*)d_in[1];
    float* out = (float*)d_out;
    unsigned char* ws = (unsigned char*)d_ws;

    int*   counter = (int*)(ws + CTR_OFF);
    float* csq     = (float*)(ws + CSQ_OFF);
    unsigned char* cbias = ws + CB4_OFF;
    unsigned char* cbh = ws + CBH_OFF;
    unsigned char* cbl = ws + CBL_OFF;
    int* list  = (int*)(ws + LIST_OFF);

    prep_csq<<<K_CB / 256, 256, 0, stream>>>(cb, csq, cbias, counter);
    prep_split<<<(K_CB * 8) / 256, 256, 0, stream>>>(cb, cbh, cbl);
    vq_main_mfma<<<N_ROWS / 128, 256, 0, stream>>>(z, cb, cbh, cbl, cbias,
                                                   list, counter, out);
    repair_kernel<<<2048, 256, 0, stream>>>(z, cb, csq, list, counter, out);
}